// Round 8
// baseline (601.846 us; speedup 1.0000x reference)
//
#include <hip/hip_runtime.h>
#include <hip/hip_bf16.h>

#define BATCH 2
#define CH 256
#define NH 4
#define HD 64
#define NGROUP 8
#define CPG 32
#define NTOK 4096
#define EPSV 1e-5f
// scale = hd^-0.5 = 0.125, folded with log2(e) so P = exp2(q'.k)
#define QSCALE 0.1803368801111204f
#define NSPLIT 4
#define NBLK 1024

typedef __attribute__((ext_vector_type(8))) short short8;
typedef __attribute__((ext_vector_type(4))) short s4bf;
typedef __attribute__((ext_vector_type(4))) float float4v;

__device__ __forceinline__ unsigned short f2bf(float f) {
    union { float f; unsigned u; } v; v.f = f;
    unsigned r = v.u + 0x7FFF + ((v.u >> 16) & 1);
    return (unsigned short)(r >> 16);
}
__device__ __forceinline__ unsigned short f2bf_fast(float f) {
    union { float f; unsigned u; } v; v.f = f;
    return (unsigned short)((v.u + 0x8000u) >> 16);
}
__device__ __forceinline__ float bf2f(unsigned short u) {
    union { unsigned u; float f; } v; v.u = ((unsigned)u) << 16;
    return v.f;
}
// pack two f32 -> one VGPR holding two bf16 (RNE, same results as f2bf)
__device__ __forceinline__ unsigned pk2bf(float a, float b) {
#if __has_builtin(__builtin_amdgcn_cvt_pk_bf16_f32)
    typedef __attribute__((ext_vector_type(2))) __bf16 bf2v;
    bf2v p = __builtin_amdgcn_cvt_pk_bf16_f32(a, b);
    union { bf2v v; unsigned u; } c; c.v = p;
    return c.u;
#else
    return (unsigned)f2bf_fast(a) | ((unsigned)f2bf_fast(b) << 16);
#endif
}

// async global->LDS DMA, 16B per lane; dst must be wave-uniform (HW adds lane*16)
#define GL2LDS(g, l) __builtin_amdgcn_global_load_lds( \
    (const __attribute__((address_space(1))) void*)(g), \
    (__attribute__((address_space(3))) void*)(l), 16, 0, 0)

// ---- software grid barrier (sense-reversing, device-scope atomics) ----
// Safe because the grid is exactly co-resident: 1024 blocks = 4/CU x 256 CU,
// launch_bounds(256,4) caps VGPR at 128, LDS 35840*4 = 140KB <= 160KB.
__device__ __forceinline__ void gbar(unsigned* bar) {
    __syncthreads();
    if (threadIdx.x == 0) {
        __threadfence();   // release: prior global writes -> device scope
        unsigned my = __hip_atomic_load(&bar[1], __ATOMIC_RELAXED, __HIP_MEMORY_SCOPE_AGENT);
        unsigned old = __hip_atomic_fetch_add(&bar[0], 1u, __ATOMIC_ACQ_REL, __HIP_MEMORY_SCOPE_AGENT);
        if (old == NBLK - 1u) {
            __hip_atomic_store(&bar[0], 0u, __ATOMIC_RELAXED, __HIP_MEMORY_SCOPE_AGENT);
            __hip_atomic_fetch_add(&bar[1], 1u, __ATOMIC_RELEASE, __HIP_MEMORY_SCOPE_AGENT);
        } else {
            while (__hip_atomic_load(&bar[1], __ATOMIC_ACQUIRE, __HIP_MEMORY_SCOPE_AGENT) == my)
                __builtin_amdgcn_s_sleep(8);
        }
        __threadfence();   // acquire: other blocks' writes visible
    }
    __syncthreads();
}

// ---------------- prep: gn_partial + wcvt + barrier-state init ----------------
__global__ void prep(const float* __restrict__ x,
                     const float* __restrict__ qkv_w, const float* __restrict__ qkv_b,
                     const float* __restrict__ proj_w,
                     float* __restrict__ psum, float* __restrict__ psq,
                     unsigned short* __restrict__ wq, float* __restrict__ bq,
                     unsigned short* __restrict__ wp, unsigned* __restrict__ bar) {
    int bx = blockIdx.x;
    int t = threadIdx.x;
    if (bx == 0 && t == 0) { bar[0] = 0u; bar[1] = 0u; }
    if (bx < 256) {
        int s = bx & 15, g = (bx >> 4) & 7, b = bx >> 7;
        const float* base = x + ((size_t)(b * CH + g * CPG)) * NTOK + (size_t)s * 8192;
        float sum = 0.f, sq = 0.f;
        const float4v* p4 = (const float4v*)base;
        for (int i = 0; i < 8; ++i) {
            float4v v = p4[t + i * 256];
            for (int j = 0; j < 4; ++j) { sum += v[j]; sq += v[j] * v[j]; }
        }
        for (int off = 32; off; off >>= 1) {
            sum += __shfl_down(sum, off, 64);
            sq  += __shfl_down(sq,  off, 64);
        }
        __shared__ float ls[8];
        int wave = t >> 6, lane = t & 63;
        if (lane == 0) { ls[wave * 2] = sum; ls[wave * 2 + 1] = sq; }
        __syncthreads();
        if (t == 0) {
            float S = 0.f, Q = 0.f;
            for (int w = 0; w < 4; ++w) { S += ls[w * 2]; Q += ls[w * 2 + 1]; }
            int idx = (b * NGROUP + g) * 16 + s;
            psum[idx] = S; psq[idx] = Q;
        }
    } else {
        int idx = (bx - 256) * 256 + t;
        int stride = 256 * 256;
        for (int i = idx; i < 3 * CH * CH; i += stride) {
            float f = qkv_w[i];
            if (i < CH * CH) f *= QSCALE;
            wq[i] = f2bf(f);
        }
        for (int i = idx; i < CH * CH; i += stride) wp[i] = f2bf(proj_w[i]);
        for (int i = idx; i < 3 * CH; i += stride) {
            float f = qkv_b[i];
            if (i < CH) f *= QSCALE;
            bq[i] = f;
        }
    }
}

// =====================================================================================
// MEGA: qkv(+fused GN) -> gbar -> flash-attn -> gbar -> proj. Regular launch (graph-
// capture-safe); phase internals are the R5/R6 verified code verbatim. Removes two
// kernel boundaries from the serial chain (was 4 launches, now 2).
// =====================================================================================
__global__ __launch_bounds__(256, 4) void mega(
        const float* __restrict__ x, const float* __restrict__ nw,
        const float* __restrict__ nb_,
        const float* __restrict__ proj_b, float* __restrict__ out,
        const float* __restrict__ psum, const float* __restrict__ psq,
        const unsigned short* __restrict__ wq, const float* __restrict__ bq,
        const unsigned short* __restrict__ wp,
        unsigned short* __restrict__ qT, unsigned short* __restrict__ kT,
        unsigned short* __restrict__ vv,
        unsigned short* __restrict__ opb, float* __restrict__ lpb,
        unsigned* __restrict__ bar) {
    const int bx = blockIdx.x;          // 0..1023
    const int t = threadIdx.x;
    const int wave = t >> 6, lane = t & 63;
    const int l15 = lane & 15, quad = lane >> 4;

    // shared overlay: P2 bt[64*264]+wch[256]+bch[256] | P3 kbuf2+vbuf2 | P4 bt+rl
    __shared__ __align__(16) char smem[35840];

    // ================= P2: QKV GEMM with fused GroupNorm (1536 units) ================
    {
        unsigned short* bt = (unsigned short*)smem;            // 64*264 shorts = 33792 B
        float* wch = (float*)(smem + 33792);
        float* bch = (float*)(smem + 34816);
        for (int u = bx; u < 1536; u += NBLK) {
            int xcd = u & 7, j = u >> 3;
            int ob = j % 12;
            int pp = xcd + 8 * (j / 12);
            int nb = pp & 63;
            int b  = pp >> 6;
            int o0 = ob * 64 + wave * 16;
            __syncthreads();               // previous unit fully done with smem
            {
                int c = t, gg = c >> 5;
                float S = 0.f, Q = 0.f;
                for (int s = 0; s < 16; ++s) {
                    S += psum[(b * NGROUP + gg) * 16 + s];
                    Q += psq[(b * NGROUP + gg) * 16 + s];
                }
                const float M = (float)(CPG * NTOK);
                float mean = S / M;
                float inv  = rsqrtf(Q / M - mean * mean + EPSV);
                float w = nw[c] * inv;
                wch[c] = w;
                bch[c] = nb_[c] - mean * w;
            }
            short8 aW[8];
            {
                const unsigned short* wr = wq + (size_t)(o0 + l15) * CH + quad * 8;
                for (int kc = 0; kc < 8; ++kc) aW[kc] = *(const short8*)(wr + kc * 32);
            }
            __syncthreads();               // wch/bch ready
            {
                int n = t & 63, jj = t >> 6;
                const float* xb = x + (size_t)b * CH * NTOK + (size_t)nb * 64 + n;
                for (int i = 0; i < 16; ++i) {
                    int c0 = i * 16 + jj * 4;
                    float h0 = xb[(size_t)(c0 + 0) * NTOK] * wch[c0 + 0] + bch[c0 + 0];
                    float h1 = xb[(size_t)(c0 + 1) * NTOK] * wch[c0 + 1] + bch[c0 + 1];
                    float h2 = xb[(size_t)(c0 + 2) * NTOK] * wch[c0 + 2] + bch[c0 + 2];
                    float h3 = xb[(size_t)(c0 + 3) * NTOK] * wch[c0 + 3] + bch[c0 + 3];
                    union { s4bf v; unsigned u[2]; } pk;
                    pk.u[0] = pk2bf(h0, h1);
                    pk.u[1] = pk2bf(h2, h3);
                    *(s4bf*)(bt + n * 264 + c0) = pk.v;
                }
            }
            __syncthreads();

            float4v acc[4];
            for (int nt = 0; nt < 4; ++nt) for (int r = 0; r < 4; ++r) acc[nt][r] = 0.f;
            for (int kc = 0; kc < 8; ++kc) {
                for (int nt = 0; nt < 4; ++nt) {
                    short8 pb = *(const short8*)(bt + (nt * 16 + l15) * 264 + kc * 32 + quad * 8);
                    acc[nt] = __builtin_amdgcn_mfma_f32_16x16x32_bf16(aW[kc], pb, acc[nt], 0, 0, 0);
                }
            }
            int seg = ob >> 2;             // 0=q (pre-scaled), 1=k, 2=v
            if (seg < 2) {
                int hh = ob & 3;
                unsigned short* dst = (seg == 0) ? qT : kT;
                unsigned short* ot = bt;   // reuse as transpose buf (stride 72 shorts)
                __syncthreads();           // everyone done reading bt
                for (int nt = 0; nt < 4; ++nt) {
                    int ob_ = o0 + quad * 4;
                    s4bf pk;
                    for (int r = 0; r < 4; ++r)
                        pk[r] = (short)f2bf(acc[nt][r] + bq[ob_ + r]);
                    int ci = wave * 16 + quad * 4;
                    *(s4bf*)(ot + (nt * 16 + l15) * 72 + ci) = pk;
                }
                __syncthreads();
                for (int ii = 0; ii < 2; ++ii) {
                    int id2 = ii * 256 + t;
                    int n = id2 >> 3, c16 = id2 & 7;
                    short8 row = *(const short8*)(ot + n * 72 + c16 * 8);
                    *(short8*)(dst + (((size_t)b * NH + hh) * NTOK + (size_t)nb * 64 + n) * HD + c16 * 8) = row;
                }
            } else {
                for (int nt = 0; nt < 4; ++nt) {
                    int n = nb * 64 + nt * 16 + l15;
                    for (int r = 0; r < 4; ++r) {
                        int o = o0 + quad * 4 + r;
                        float val = acc[nt][r] + bq[o];
                        int cch = o & 255;
                        int hh = cch >> 6, ci = cch & 63;
                        vv[(((size_t)b * NH + hh) * HD + ci) * NTOK + n] = f2bf(val);
                    }
                }
            }
        }
    }
    gbar(bar);

    // ================= P3: flash attention (1024 units, verbatim R5 structure) =======
    {
        int f = bx;
        int xcd = f & 7, j = f >> 3;
        int nb = j >> 2;
        int g  = xcd + 8 * (j & 3);
        int h  = g & 3;
        int zb = g >> 2;
        int sp = zb & 3, b = zb >> 2;
        int n0 = nb * 128 + wave * 32;
        int kv0 = sp * (NTOK / NSPLIT);

        unsigned short* opart = opb + (size_t)sp * ((size_t)BATCH * NTOK * CH);
        float* lpart = lpb + (size_t)sp * (BATCH * NH * NTOK);

        const unsigned short* qbh = qT + ((size_t)(b * NH + h)) * NTOK * HD;
        const unsigned short* kbh = kT + ((size_t)(b * NH + h)) * NTOK * HD;
        const unsigned short* vbh = vv + ((size_t)(b * NH + h)) * HD * NTOK;

        unsigned short* kbufs = (unsigned short*)smem;           // 2 x 4096 shorts
        unsigned short* vbufs = (unsigned short*)(smem + 16384); // 2 x 4096 shorts

        short8 aQ[2][2];
        for (int mt = 0; mt < 2; ++mt) {
            aQ[mt][0] = *(const short8*)(qbh + (size_t)(n0 + mt * 16 + l15) * HD + quad * 8);
            aQ[mt][1] = *(const short8*)(qbh + (size_t)(n0 + mt * 16 + l15) * HD + 32 + quad * 8);
        }

        float l_p[2] = {0.f, 0.f};
        float4v o_acc[2][4];
        for (int mt = 0; mt < 2; ++mt)
            for (int ct = 0; ct < 4; ++ct)
                for (int r = 0; r < 4; ++r) o_acc[mt][ct][r] = 0.f;
        const float4v ZERO = {0.f, 0.f, 0.f, 0.f};

        #define STAGE_TILE(kb_, vb_, ms_)                                              \
            do {                                                                       \
                _Pragma("unroll")                                                      \
                for (int i = 0; i < 2; ++i) {                                          \
                    int slot = (wave * 2 + i) * 64 + lane;                             \
                    int r = slot >> 3, c = slot & 7;                                   \
                    GL2LDS(kbh + (size_t)((ms_) + r) * HD + ((c ^ (r & 7)) << 3),      \
                           (kb_) + (wave * 2 + i) * 512);                              \
                }                                                                      \
                _Pragma("unroll")                                                      \
                for (int i = 0; i < 2; ++i) {                                          \
                    int slot = (wave * 2 + i) * 64 + lane;                             \
                    int r = slot >> 3, c = slot & 7;                                   \
                    GL2LDS(vbh + (size_t)r * NTOK + (ms_) + ((c ^ (r & 7)) << 3),      \
                           (vb_) + (wave * 2 + i) * 512);                              \
                }                                                                      \
            } while (0)

        STAGE_TILE(kbufs, vbufs, kv0);
        int cur = 0;

        for (int ms = kv0; ms < kv0 + NTOK / NSPLIT; ms += 64) {
            asm volatile("s_waitcnt vmcnt(0)" ::: "memory");
            __syncthreads();
            if (ms + 64 < kv0 + NTOK / NSPLIT)
                STAGE_TILE(kbufs + (cur ^ 1) * 4096, vbufs + (cur ^ 1) * 4096, ms + 64);
            const unsigned short* kb = kbufs + cur * 4096;
            const unsigned short* vb = vbufs + cur * 4096;

            float4v s[2][4];
            __builtin_amdgcn_s_setprio(1);
#pragma unroll
            for (int nt = 0; nt < 4; ++nt) {
                int krow = nt * 16 + l15;
                int r7 = krow & 7;
                short8 ak0 = *(const short8*)(kb + krow * 64 + ((quad ^ r7) << 3));
                short8 ak1 = *(const short8*)(kb + krow * 64 + (((quad + 4) ^ r7) << 3));
#pragma unroll
                for (int mt = 0; mt < 2; ++mt) {
                    float4v z = __builtin_amdgcn_mfma_f32_16x16x32_bf16(ak0, aQ[mt][0], ZERO, 0, 0, 0);
                    z = __builtin_amdgcn_mfma_f32_16x16x32_bf16(ak1, aQ[mt][1], z, 0, 0, 0);
                    s[mt][nt] = z;
                }
            }
            __builtin_amdgcn_s_setprio(0);
            s4bf aP[2][4];
#pragma unroll
            for (int mt = 0; mt < 2; ++mt) {
#pragma unroll
                for (int nt = 0; nt < 4; ++nt) {
                    float e0 = __builtin_amdgcn_exp2f(s[mt][nt][0]);
                    float e1 = __builtin_amdgcn_exp2f(s[mt][nt][1]);
                    float e2 = __builtin_amdgcn_exp2f(s[mt][nt][2]);
                    float e3 = __builtin_amdgcn_exp2f(s[mt][nt][3]);
                    l_p[mt] += (e0 + e1) + (e2 + e3);
                    union { s4bf v; unsigned u[2]; } c;
                    c.u[0] = pk2bf(e0, e1);
                    c.u[1] = pk2bf(e2, e3);
                    aP[mt][nt] = c.v;
                }
            }
            __builtin_amdgcn_s_setprio(1);
#pragma unroll
            for (int ct = 0; ct < 4; ++ct) {
#pragma unroll
                for (int nt = 0; nt < 4; ++nt) {
                    int vr = ct * 16 + l15;
                    int c8 = nt * 2 + (quad >> 1);
                    s4bf bv = *(const s4bf*)(vb + vr * 64 +
                                             ((c8 ^ (vr & 7)) << 3) + ((quad & 1) << 2));
#pragma unroll
                    for (int mt = 0; mt < 2; ++mt)
                        o_acc[mt][ct] = __builtin_amdgcn_mfma_f32_16x16x16bf16_1k(aP[mt][nt], bv, o_acc[mt][ct], 0, 0, 0);
                }
            }
            __builtin_amdgcn_s_setprio(0);
            cur ^= 1;
        }
        for (int mt = 0; mt < 2; ++mt) {
            l_p[mt] += __shfl_xor(l_p[mt], 16, 64);
            l_p[mt] += __shfl_xor(l_p[mt], 32, 64);
        }
        for (int mt = 0; mt < 2; ++mt) {
            for (int ct = 0; ct < 4; ++ct) {
                for (int r = 0; r < 4; ++r) {
                    int n = n0 + mt * 16 + quad * 4 + r;
                    int cg = h * HD + ct * 16 + l15;
                    opart[((size_t)b * NTOK + n) * CH + cg] = f2bf(o_acc[mt][ct][r]);
                }
            }
            if (lane < 16)
                lpart[((size_t)(b * NH + h)) * NTOK + n0 + mt * 16 + lane] = l_p[mt];
        }
    }
    gbar(bar);

    // ================= P4: proj GEMM + split-combine + bias + residual (512 units) ===
    if (bx < 512) {
        int f = bx;
        int xcd = f & 7, j = f >> 3;
        int cb = j & 3;
        int pp = xcd + 8 * (j >> 2);
        int nb = pp & 63;
        int b  = pp >> 6;
        int c0 = cb * 64 + wave * 16;
        const size_t OP = (size_t)BATCH * NTOK * CH;
        const size_t LP = (size_t)BATCH * NH * NTOK;

        unsigned short* bt = (unsigned short*)smem;
        float* rl = (float*)(smem + 33792);

        short8 aW[8];
        {
            const unsigned short* wr = wp + (size_t)(c0 + l15) * CH + quad * 8;
            for (int kc = 0; kc < 8; ++kc) aW[kc] = *(const short8*)(wr + kc * 32);
        }
        {
            int r = t >> 2, h = t & 3;
            size_t lidx = ((size_t)(b * NH + h)) * NTOK + nb * 64 + r;
            float ls = (lpb[lidx] + lpb[LP + lidx]) + (lpb[2 * LP + lidx] + lpb[3 * LP + lidx]);
            rl[r * 4 + h] = 1.0f / ls;
        }
        __syncthreads();
        for (int p2 = 0; p2 < 8; ++p2) {
            int slot = p2 * 256 + t;
            int r = slot >> 5, c = slot & 31;
            size_t base = ((size_t)b * NTOK + nb * 64 + r) * CH + c * 8;
            short8 o0 = *(const short8*)(opb + base);
            short8 o1 = *(const short8*)(opb + OP + base);
            short8 o2 = *(const short8*)(opb + 2 * OP + base);
            short8 o3 = *(const short8*)(opb + 3 * OP + base);
            float rinv = rl[r * 4 + (c >> 3)];
            short8 m;
            for (int jj = 0; jj < 8; ++jj) {
                float ff = (bf2f((unsigned short)o0[jj]) + bf2f((unsigned short)o1[jj]))
                         + (bf2f((unsigned short)o2[jj]) + bf2f((unsigned short)o3[jj]));
                m[jj] = (short)f2bf(ff * rinv);
            }
            *(short8*)(bt + r * 264 + c * 8) = m;
        }
        __syncthreads();

        float4v acc[4];
        for (int nt = 0; nt < 4; ++nt) for (int r = 0; r < 4; ++r) acc[nt][r] = 0.f;
        for (int kc = 0; kc < 8; ++kc) {
            for (int nt = 0; nt < 4; ++nt) {
                short8 pb = *(const short8*)(bt + (nt * 16 + l15) * 264 + kc * 32 + quad * 8);
                acc[nt] = __builtin_amdgcn_mfma_f32_16x16x32_bf16(aW[kc], pb, acc[nt], 0, 0, 0);
            }
        }
        for (int nt = 0; nt < 4; ++nt) {
            int n = nb * 64 + nt * 16 + l15;
            for (int r = 0; r < 4; ++r) {
                int cc = c0 + quad * 4 + r;
                size_t idx = ((size_t)(b * CH + cc)) * NTOK + n;
                out[idx] = acc[nt][r] + proj_b[cc] + x[idx];
            }
        }
    }
}

extern "C" void kernel_launch(void* const* d_in, const int* in_sizes, int n_in,
                              void* d_out, int out_size, void* d_ws, size_t ws_size,
                              hipStream_t stream) {
    const float* x      = (const float*)d_in[0];
    const float* norm_w = (const float*)d_in[1];
    const float* norm_b = (const float*)d_in[2];
    const float* qkv_w  = (const float*)d_in[3];
    const float* qkv_b  = (const float*)d_in[4];
    const float* proj_w = (const float*)d_in[5];
    const float* proj_b = (const float*)d_in[6];
    float* out = (float*)d_out;

    char* ws = (char*)d_ws;
    float* psum  = (float*)ws;                       // 256 f
    float* psq   = (float*)(ws + 1024);              // 256 f
    unsigned* bar = (unsigned*)(ws + 2048);          // 2 u32 (barrier state)
    float* bqs   = (float*)(ws + 4096);              // 768 f
    unsigned short* wqb = (unsigned short*)(ws + 8192);        // 3*256*256 bf16
    unsigned short* wpb = (unsigned short*)(ws + 401408);      // 256*256 bf16
    float* lpb = (float*)(ws + 532480);              // 4 * 2*4*4096 f
    const size_t MB4 = 4194304;
    unsigned short* opb = (unsigned short*)(ws + 2097152);     // 4 x 4 MB partials
    unsigned short* qT = (unsigned short*)(ws + 2097152 + 4 * MB4);
    unsigned short* kT = (unsigned short*)(ws + 2097152 + 5 * MB4);
    unsigned short* vv = (unsigned short*)(ws + 2097152 + 6 * MB4);

    prep<<<dim3(512), dim3(256), 0, stream>>>(x, qkv_w, qkv_b, proj_w, psum, psq,
                                              wqb, bqs, wpb, bar);
    mega<<<dim3(NBLK), dim3(256), 0, stream>>>(x, norm_w, norm_b, proj_b, out,
                                               psum, psq, wqb, bqs, wpb,
                                               qT, kT, vv, opb, lpb, bar);
}

// Round 9
// 146.023 us; speedup vs baseline: 4.1216x; 4.1216x over previous
//
#include <hip/hip_runtime.h>
#include <hip/hip_bf16.h>

#define BATCH 2
#define CH 256
#define NH 4
#define HD 64
#define NGROUP 8
#define CPG 32
#define NTOK 4096
#define EPSV 1e-5f
// scale = hd^-0.5 = 0.125, folded with log2(e) so P = exp2(q'.k)
#define QSCALE 0.1803368801111204f
#define NSPLIT 4

typedef __attribute__((ext_vector_type(8))) short short8;
typedef __attribute__((ext_vector_type(4))) short s4bf;
typedef __attribute__((ext_vector_type(4))) float float4v;

__device__ __forceinline__ unsigned short f2bf(float f) {
    union { float f; unsigned u; } v; v.f = f;
    unsigned r = v.u + 0x7FFF + ((v.u >> 16) & 1);
    return (unsigned short)(r >> 16);
}
__device__ __forceinline__ unsigned short f2bf_fast(float f) {
    union { float f; unsigned u; } v; v.f = f;
    return (unsigned short)((v.u + 0x8000u) >> 16);
}
__device__ __forceinline__ float bf2f(unsigned short u) {
    union { unsigned u; float f; } v; v.u = ((unsigned)u) << 16;
    return v.f;
}
// pack two f32 -> one VGPR holding two bf16 (RNE, same results as f2bf)
__device__ __forceinline__ unsigned pk2bf(float a, float b) {
#if __has_builtin(__builtin_amdgcn_cvt_pk_bf16_f32)
    typedef __attribute__((ext_vector_type(2))) __bf16 bf2v;
    bf2v p = __builtin_amdgcn_cvt_pk_bf16_f32(a, b);
    union { bf2v v; unsigned u; } c; c.v = p;
    return c.u;
#else
    return (unsigned)f2bf_fast(a) | ((unsigned)f2bf_fast(b) << 16);
#endif
}

// async global->LDS DMA, 16B per lane; dst must be wave-uniform (HW adds lane*16)
#define GL2LDS(g, l) __builtin_amdgcn_global_load_lds( \
    (const __attribute__((address_space(1))) void*)(g), \
    (__attribute__((address_space(3))) void*)(l), 16, 0, 0)

// ---------------- prep: fused wcvt + gn_partial (independent work) ----------------
__global__ void prep(const float* __restrict__ x,
                     const float* __restrict__ qkv_w, const float* __restrict__ qkv_b,
                     const float* __restrict__ proj_w,
                     float* __restrict__ psum, float* __restrict__ psq,
                     unsigned short* __restrict__ wq, float* __restrict__ bq,
                     unsigned short* __restrict__ wp) {
    int bx = blockIdx.x;
    int t = threadIdx.x;
    if (bx < 256) {
        // -------- gn_partial --------
        int s = bx & 15, g = (bx >> 4) & 7, b = bx >> 7;
        const float* base = x + ((size_t)(b * CH + g * CPG)) * NTOK + (size_t)s * 8192;
        float sum = 0.f, sq = 0.f;
        const float4v* p4 = (const float4v*)base;
        for (int i = 0; i < 8; ++i) {
            float4v v = p4[t + i * 256];
            for (int j = 0; j < 4; ++j) { sum += v[j]; sq += v[j] * v[j]; }
        }
        for (int off = 32; off; off >>= 1) {
            sum += __shfl_down(sum, off, 64);
            sq  += __shfl_down(sq,  off, 64);
        }
        __shared__ float ls[8];
        int wave = t >> 6, lane = t & 63;
        if (lane == 0) { ls[wave * 2] = sum; ls[wave * 2 + 1] = sq; }
        __syncthreads();
        if (t == 0) {
            float S = 0.f, Q = 0.f;
            for (int w = 0; w < 4; ++w) { S += ls[w * 2]; Q += ls[w * 2 + 1]; }
            int idx = (b * NGROUP + g) * 16 + s;
            psum[idx] = S; psq[idx] = Q;
        }
    } else {
        // -------- wcvt --------
        int idx = (bx - 256) * 256 + t;
        int stride = 256 * 256;
        for (int i = idx; i < 3 * CH * CH; i += stride) {
            float f = qkv_w[i];
            if (i < CH * CH) f *= QSCALE;
            wq[i] = f2bf(f);
        }
        for (int i = idx; i < CH * CH; i += stride) wp[i] = f2bf(proj_w[i]);
        for (int i = idx; i < 3 * CH; i += stride) {
            float f = qkv_b[i];
            if (i < CH) f *= QSCALE;
            bq[i] = f;
        }
    }
}

// ---------------- QKV GEMM with fused GroupNorm + transposed q/k/v stores ----------------
// Round-12: (R6 base) + V epilogue now also transposed via LDS -> coalesced 128B
// short8 row stores into vv[b,h,d,n] (was 16x 2B scatter at 8KB stride / 32B sectors).
__global__ __launch_bounds__(256) void qkv_gemm(const float* __restrict__ x,
        const float* __restrict__ nw, const float* __restrict__ nb_,
        const float* __restrict__ psum, const float* __restrict__ psq,
        const unsigned short* __restrict__ wq, const float* __restrict__ bq,
        unsigned short* __restrict__ qT, unsigned short* __restrict__ kT,
        unsigned short* __restrict__ vv) {
    // XCD remap: all 12 ob-blocks of one (nb,b) tile on the same XCD (shares x tile in L2)
    int f = blockIdx.x + 64 * blockIdx.y + 768 * blockIdx.z;   // 0..1535
    int xcd = f & 7, j = f >> 3;        // j: 0..191
    int ob = j % 12;                    // 0..11
    int p  = xcd + 8 * (j / 12);        // 0..127
    int nb = p & 63;                    // 0..63
    int b  = p >> 6;                    // 0..1
    int t = threadIdx.x;
    int wave = t >> 6, lane = t & 63;
    int l15 = lane & 15, quad = lane >> 4;
    int o0 = ob * 64 + wave * 16;

    __shared__ __align__(16) unsigned short bt[64 * 264];   // B tile; reused as transpose buf
    __shared__ float wch[256], bch[256];                     // per-channel affine

    // ---- per-channel scale/shift from partial stats (one channel per thread)
    {
        int c = t;
        int gg = c >> 5;
        float S = 0.f, Q = 0.f;
        for (int s = 0; s < 16; ++s) {
            S += psum[(b * NGROUP + gg) * 16 + s];
            Q += psq[(b * NGROUP + gg) * 16 + s];
        }
        const float M = (float)(CPG * NTOK);
        float mean = S / M;
        float inv  = rsqrtf(Q / M - mean * mean + EPSV);
        float w = nw[c] * inv;
        wch[c] = w;
        bch[c] = nb_[c] - mean * w;
    }

    short8 aW[8];
    {
        const unsigned short* wr = wq + (size_t)(o0 + l15) * CH + quad * 8;
        for (int kc = 0; kc < 8; ++kc) aW[kc] = *(const short8*)(wr + kc * 32);
    }
    __syncthreads();   // wch/bch ready

    // ---- stage normalized B tile [64 n][256 c] bf16 directly from x
    {
        int n = t & 63, jj = t >> 6;     // jj: 0..3
        const float* xb = x + (size_t)b * CH * NTOK + (size_t)nb * 64 + n;
        for (int i = 0; i < 16; ++i) {
            int c0 = i * 16 + jj * 4;
            float h0 = xb[(size_t)(c0 + 0) * NTOK] * wch[c0 + 0] + bch[c0 + 0];
            float h1 = xb[(size_t)(c0 + 1) * NTOK] * wch[c0 + 1] + bch[c0 + 1];
            float h2 = xb[(size_t)(c0 + 2) * NTOK] * wch[c0 + 2] + bch[c0 + 2];
            float h3 = xb[(size_t)(c0 + 3) * NTOK] * wch[c0 + 3] + bch[c0 + 3];
            union { s4bf v; unsigned u[2]; } pk;
            pk.u[0] = pk2bf(h0, h1);
            pk.u[1] = pk2bf(h2, h3);
            *(s4bf*)(bt + n * 264 + c0) = pk.v;
        }
    }
    __syncthreads();

    float4v acc[4];
    for (int nt = 0; nt < 4; ++nt) for (int r = 0; r < 4; ++r) acc[nt][r] = 0.f;
    for (int kc = 0; kc < 8; ++kc) {
        for (int nt = 0; nt < 4; ++nt) {
            short8 pb = *(const short8*)(bt + (nt * 16 + l15) * 264 + kc * 32 + quad * 8);
            acc[nt] = __builtin_amdgcn_mfma_f32_16x16x32_bf16(aW[kc], pb, acc[nt], 0, 0, 0);
        }
    }
    // seg is block-uniform: o in [ob*64, ob*64+64)
    int seg = ob >> 2;         // 0=q (pre-scaled), 1=k, 2=v
    if (seg < 2) {
        // one head's [64 n][64 hd] tile -> transpose via LDS, coalesced row stores
        int hh = ob & 3;
        unsigned short* dst = (seg == 0) ? qT : kT;
        unsigned short* ot = bt;             // reuse (stride 72 shorts)
        __syncthreads();                     // everyone done reading bt
        for (int nt = 0; nt < 4; ++nt) {
            int ob_ = o0 + quad * 4;
            s4bf pk;
            for (int r = 0; r < 4; ++r)
                pk[r] = (short)f2bf(acc[nt][r] + bq[ob_ + r]);
            int ci = wave * 16 + quad * 4;   // channel within head
            *(s4bf*)(ot + (nt * 16 + l15) * 72 + ci) = pk;
        }
        __syncthreads();
        for (int ii = 0; ii < 2; ++ii) {
            int id2 = ii * 256 + t;
            int n = id2 >> 3, c16 = id2 & 7;
            short8 row = *(const short8*)(ot + n * 72 + c16 * 8);
            *(short8*)(dst + (((size_t)b * NH + hh) * NTOK + (size_t)nb * 64 + n) * HD + c16 * 8) = row;
        }
    } else {
        // V: one head's [64 ci][64 n] tile in vv[b,h,d,n] -> transpose via LDS,
        // coalesced 128B row stores (was 2B scatter at 8KB stride)
        int hh = ob & 3;
        unsigned short* ot = bt;             // [ci=64][n], stride 72 shorts
        __syncthreads();                     // everyone done reading bt
        for (int nt = 0; nt < 4; ++nt) {
            int cib = wave * 16 + quad * 4;  // channel within head (row)
            int ob_ = o0 + quad * 4;
            for (int r = 0; r < 4; ++r)
                ot[(cib + r) * 72 + nt * 16 + l15] = f2bf(acc[nt][r] + bq[ob_ + r]);
        }
        __syncthreads();
        for (int ii = 0; ii < 2; ++ii) {
            int id2 = ii * 256 + t;
            int ci = id2 >> 3, c16 = id2 & 7;
            short8 row = *(const short8*)(ot + ci * 72 + c16 * 8);
            *(short8*)(vv + (((size_t)b * NH + hh) * HD + ci) * NTOK + (size_t)nb * 64 + c16 * 8) = row;
        }
    }
}

// ---------------- Flash attention: S^T trick (register P->PV), 64-key tiles, split x4 ----
// Round-12: R5/R6-verified structure + incremental DMA source pointers (the per-tile
// source delta is constant: K +64*HD shorts, V +64 shorts). Removes the per-tile
// slot/r/c + 64-bit address recompute (~40 VALU/tile/wave) from the VALU-bound loop
// (VALUBusy 45% > MfmaUtil 36%). All numerics / layouts / sync identical.
__global__ __launch_bounds__(256, 4) void attn_kernel(const unsigned short* __restrict__ qT,
        const unsigned short* __restrict__ kT, const unsigned short* __restrict__ vv,
        unsigned short* __restrict__ opb, float* __restrict__ lpb) {
    // ---- bijective XCD swizzle: f = flat id; hw assigns XCD = f & 7 (round-robin).
    // group g = h + 4*zb (32 groups share one K/V chunk); give each XCD 4 whole groups.
    int f = blockIdx.x + 32 * blockIdx.y + 128 * blockIdx.z;   // 0..1023
    int xcd = f & 7, j = f >> 3;                                // j: 0..127
    int nb = j >> 2;                                            // 0..31
    int g  = xcd + 8 * (j & 3);                                 // 0..31
    int h  = g & 3;
    int zb = g >> 2;
    int sp = zb & 3, b = zb >> 2;
    int t = threadIdx.x, wave = t >> 6, lane = t & 63;
    int l15 = lane & 15, quad = lane >> 4;
    int n0 = nb * 128 + wave * 32;     // wave owns 2 m-tiles of 16 rows
    int kv0 = sp * (NTOK / NSPLIT);

    unsigned short* opart = opb + (size_t)sp * ((size_t)BATCH * NTOK * CH);
    float* lpart = lpb + (size_t)sp * (BATCH * NH * NTOK);

    const unsigned short* qbh = qT + ((size_t)(b * NH + h)) * NTOK * HD;
    const unsigned short* kbh = kT + ((size_t)(b * NH + h)) * NTOK * HD;
    const unsigned short* vbh = vv + ((size_t)(b * NH + h)) * HD * NTOK;

    // double-buffered tiles (32 KB total)
    __shared__ __align__(16) unsigned short kbuf[2][64 * 64];
    __shared__ __align__(16) unsigned short vbuf[2][64 * 64];

    short8 aQ[2][2];   // B-fragment of QK: B[q-row=l15][hd k=quad*8+j]
    for (int mt = 0; mt < 2; ++mt) {
        aQ[mt][0] = *(const short8*)(qbh + (size_t)(n0 + mt * 16 + l15) * HD + quad * 8);
        aQ[mt][1] = *(const short8*)(qbh + (size_t)(n0 + mt * 16 + l15) * HD + 32 + quad * 8);
    }

    float l_p[2] = {0.f, 0.f};         // per-lane partial denom (q-row = l15)
    float4v o_acc[2][4];
    for (int mt = 0; mt < 2; ++mt)
        for (int ct = 0; ct < 4; ++ct)
            for (int r = 0; r < 4; ++r) o_acc[mt][ct][r] = 0.f;
    const float4v ZERO = {0.f, 0.f, 0.f, 0.f};   // hoisted QK C-input

    // ---- per-lane DMA source pointers; constant per-tile stride (K +64*HD, V +64)
    // K tile [key r][d]: 128B rows, 8 chunks; src chunk = c ^ (r&7)
    // V tile [d r][key]: 128B rows, 8 chunks; src chunk = c ^ (r&7)
    int sl0 = (wave * 2 + 0) * 64 + lane, sl1 = (wave * 2 + 1) * 64 + lane;
    int r0 = sl0 >> 3, c0 = sl0 & 7, r1 = sl1 >> 3, c1 = sl1 & 7;
    const unsigned short* kga0 = kbh + (size_t)(kv0 + r0) * HD + ((c0 ^ (r0 & 7)) << 3);
    const unsigned short* kga1 = kbh + (size_t)(kv0 + r1) * HD + ((c1 ^ (r1 & 7)) << 3);
    const unsigned short* vga0 = vbh + (size_t)r0 * NTOK + kv0 + ((c0 ^ (r0 & 7)) << 3);
    const unsigned short* vga1 = vbh + (size_t)r1 * NTOK + kv0 + ((c1 ^ (r1 & 7)) << 3);

    #define STAGE_ADV(kb_, vb_)                                   \
        do {                                                      \
            GL2LDS(kga0, (kb_) + (wave * 2 + 0) * 512);           \
            GL2LDS(kga1, (kb_) + (wave * 2 + 1) * 512);           \
            GL2LDS(vga0, (vb_) + (wave * 2 + 0) * 512);           \
            GL2LDS(vga1, (vb_) + (wave * 2 + 1) * 512);           \
            kga0 += 64 * HD; kga1 += 64 * HD;                     \
            vga0 += 64;      vga1 += 64;                          \
        } while (0)

    STAGE_ADV(kbuf[0], vbuf[0]);
    int cur = 0;

    for (int ms = kv0; ms < kv0 + NTOK / NSPLIT; ms += 64) {
        // own DMA landed; barrier => all waves' DMA landed AND prev compute done
        asm volatile("s_waitcnt vmcnt(0)" ::: "memory");
        __syncthreads();
        if (ms + 64 < kv0 + NTOK / NSPLIT)
            STAGE_ADV(kbuf[cur ^ 1], vbuf[cur ^ 1]);   // in flight under compute
        const unsigned short* kb = kbuf[cur];
        const unsigned short* vb = vbuf[cur];

        float4v s[2][4];
        __builtin_amdgcn_s_setprio(1);
#pragma unroll
        for (int nt = 0; nt < 4; ++nt) {
            int krow = nt * 16 + l15;
            int r7 = krow & 7;
            short8 ak0 = *(const short8*)(kb + krow * 64 + ((quad ^ r7) << 3));
            short8 ak1 = *(const short8*)(kb + krow * 64 + (((quad + 4) ^ r7) << 3));
#pragma unroll
            for (int mt = 0; mt < 2; ++mt) {
                float4v z = __builtin_amdgcn_mfma_f32_16x16x32_bf16(ak0, aQ[mt][0], ZERO, 0, 0, 0);
                z = __builtin_amdgcn_mfma_f32_16x16x32_bf16(ak1, aQ[mt][1], z, 0, 0, 0);
                s[mt][nt] = z;
            }
        }
        __builtin_amdgcn_s_setprio(0);
        s4bf aP[2][4];
#pragma unroll
        for (int mt = 0; mt < 2; ++mt) {
#pragma unroll
            for (int nt = 0; nt < 4; ++nt) {
                float e0 = __builtin_amdgcn_exp2f(s[mt][nt][0]);
                float e1 = __builtin_amdgcn_exp2f(s[mt][nt][1]);
                float e2 = __builtin_amdgcn_exp2f(s[mt][nt][2]);
                float e3 = __builtin_amdgcn_exp2f(s[mt][nt][3]);
                l_p[mt] += (e0 + e1) + (e2 + e3);
                union { s4bf v; unsigned u[2]; } c;
                c.u[0] = pk2bf(e0, e1);
                c.u[1] = pk2bf(e2, e3);
                aP[mt][nt] = c.v;
            }
        }
        __builtin_amdgcn_s_setprio(1);
#pragma unroll
        for (int ct = 0; ct < 4; ++ct) {
#pragma unroll
            for (int nt = 0; nt < 4; ++nt) {
                int vr = ct * 16 + l15;
                int c8 = nt * 2 + (quad >> 1);
                s4bf bv = *(const s4bf*)(vb + vr * 64 +
                                         ((c8 ^ (vr & 7)) << 3) + ((quad & 1) << 2));
#pragma unroll
                for (int mt = 0; mt < 2; ++mt)
                    o_acc[mt][ct] = __builtin_amdgcn_mfma_f32_16x16x16bf16_1k(aP[mt][nt], bv, o_acc[mt][ct], 0, 0, 0);
            }
        }
        __builtin_amdgcn_s_setprio(0);
        cur ^= 1;
    }
    // reduce denom over the 4 quads (key blocks); q-row = l15
    for (int mt = 0; mt < 2; ++mt) {
        l_p[mt] += __shfl_xor(l_p[mt], 16, 64);
        l_p[mt] += __shfl_xor(l_p[mt], 32, 64);
    }
    // store unnormalized partial O (bf16): C-layout col=l15=d, row=quad*4+r=q-row
    for (int mt = 0; mt < 2; ++mt) {
        for (int ct = 0; ct < 4; ++ct) {
            for (int r = 0; r < 4; ++r) {
                int n = n0 + mt * 16 + quad * 4 + r;
                int cg = h * HD + ct * 16 + l15;
                opart[((size_t)b * NTOK + n) * CH + cg] = f2bf(o_acc[mt][ct][r]);
            }
        }
        if (lane < 16)
            lpart[((size_t)(b * NH + h)) * NTOK + n0 + mt * 16 + lane] = l_p[mt];
    }
}

// ---------------- Proj GEMM with fused split-combine + bias + residual ----------------
__global__ __launch_bounds__(256) void proj_gemm(const unsigned short* __restrict__ opb,
        const float* __restrict__ lpb, const unsigned short* __restrict__ wp,
        const float* __restrict__ proj_b, const float* __restrict__ x,
        float* __restrict__ out) {
    int f = blockIdx.x + 64 * blockIdx.y + 256 * blockIdx.z;   // 0..511
    int xcd = f & 7, j = f >> 3;    // j: 0..63
    int cb = j & 3;                 // 0..3
    int p  = xcd + 8 * (j >> 2);    // 0..127
    int nb = p & 63;                // 0..63
    int b  = p >> 6;                // 0..1
    int t = threadIdx.x, wave = t >> 6, lane = t & 63;
    int l15 = lane & 15, quad = lane >> 4;
    int c0 = cb * 64 + wave * 16;
    const size_t OP = (size_t)BATCH * NTOK * CH;
    const size_t LP = (size_t)BATCH * NH * NTOK;

    __shared__ __align__(16) unsigned short bt[64 * 264];
    __shared__ float rl[64 * 4];

    short8 aW[8];
    {
        const unsigned short* wr = wp + (size_t)(c0 + l15) * CH + quad * 8;
        for (int kc = 0; kc < 8; ++kc) aW[kc] = *(const short8*)(wr + kc * 32);
    }
    // per-row, per-head reciprocal denominators (normalization must precede channel-sum)
    {
        int r = t >> 2, h = t & 3;
        size_t lidx = ((size_t)(b * NH + h)) * NTOK + nb * 64 + r;
        float ls = (lpb[lidx] + lpb[LP + lidx]) + (lpb[2 * LP + lidx] + lpb[3 * LP + lidx]);
        rl[r * 4 + h] = 1.0f / ls;
    }
    __syncthreads();
    // stage normalized O tile from the 4 split partials
    for (int p2 = 0; p2 < 8; ++p2) {
        int slot = p2 * 256 + t;
        int r = slot >> 5, c = slot & 31;
        size_t base = ((size_t)b * NTOK + nb * 64 + r) * CH + c * 8;
        short8 o0 = *(const short8*)(opb + base);
        short8 o1 = *(const short8*)(opb + OP + base);
        short8 o2 = *(const short8*)(opb + 2 * OP + base);
        short8 o3 = *(const short8*)(opb + 3 * OP + base);
        float rinv = rl[r * 4 + (c >> 3)];
        short8 m;
        for (int jj = 0; jj < 8; ++jj) {
            float ff = (bf2f((unsigned short)o0[jj]) + bf2f((unsigned short)o1[jj]))
                     + (bf2f((unsigned short)o2[jj]) + bf2f((unsigned short)o3[jj]));
            m[jj] = (short)f2bf(ff * rinv);
        }
        *(short8*)(bt + r * 264 + c * 8) = m;
    }
    __syncthreads();

    float4v acc[4];
    for (int nt = 0; nt < 4; ++nt) for (int r = 0; r < 4; ++r) acc[nt][r] = 0.f;
    for (int kc = 0; kc < 8; ++kc) {
        for (int nt = 0; nt < 4; ++nt) {
            short8 pb = *(const short8*)(bt + (nt * 16 + l15) * 264 + kc * 32 + quad * 8);
            acc[nt] = __builtin_amdgcn_mfma_f32_16x16x32_bf16(aW[kc], pb, acc[nt], 0, 0, 0);
        }
    }
    for (int nt = 0; nt < 4; ++nt) {
        int n = nb * 64 + nt * 16 + l15;
        for (int r = 0; r < 4; ++r) {
            int cc = c0 + quad * 4 + r;
            size_t idx = ((size_t)(b * CH + cc)) * NTOK + n;
            out[idx] = acc[nt][r] + proj_b[cc] + x[idx];
        }
    }
}

extern "C" void kernel_launch(void* const* d_in, const int* in_sizes, int n_in,
                              void* d_out, int out_size, void* d_ws, size_t ws_size,
                              hipStream_t stream) {
    const float* x      = (const float*)d_in[0];
    const float* norm_w = (const float*)d_in[1];
    const float* norm_b = (const float*)d_in[2];
    const float* qkv_w  = (const float*)d_in[3];
    const float* qkv_b  = (const float*)d_in[4];
    const float* proj_w = (const float*)d_in[5];
    const float* proj_b = (const float*)d_in[6];
    float* out = (float*)d_out;

    char* ws = (char*)d_ws;
    float* psum  = (float*)ws;                       // 256 f
    float* psq   = (float*)(ws + 1024);              // 256 f
    float* bqs   = (float*)(ws + 4096);              // 768 f
    unsigned short* wqb = (unsigned short*)(ws + 8192);        // 3*256*256 bf16
    unsigned short* wpb = (unsigned short*)(ws + 401408);      // 256*256 bf16
    float* lpb = (float*)(ws + 532480);              // 4 * 2*4*4096 f
    const size_t MB4 = 4194304;
    unsigned short* opb = (unsigned short*)(ws + 2097152);     // 4 x 4 MB partials
    unsigned short* qT = (unsigned short*)(ws + 2097152 + 4 * MB4);
    unsigned short* kT = (unsigned short*)(ws + 2097152 + 5 * MB4);
    unsigned short* vv = (unsigned short*)(ws + 2097152 + 6 * MB4);

    prep<<<dim3(512), dim3(256), 0, stream>>>(x, qkv_w, qkv_b, proj_w, psum, psq, wqb, bqs, wpb);
    qkv_gemm<<<dim3(64, 12, BATCH), dim3(256), 0, stream>>>(x, norm_w, norm_b, psum, psq,
                                                            wqb, bqs, qT, kT, vv);
    attn_kernel<<<dim3(32, NH, BATCH * NSPLIT), dim3(256), 0, stream>>>(qT, kT, vv, opb, lpb);
    proj_gemm<<<dim3(64, 4, BATCH), dim3(256), 0, stream>>>(opb, lpb, wpb, proj_b, x, out);
}

// Round 10
// 145.620 us; speedup vs baseline: 4.1330x; 1.0028x over previous
//
#include <hip/hip_runtime.h>
#include <hip/hip_bf16.h>

#define BATCH 2
#define CH 256
#define NH 4
#define HD 64
#define NGROUP 8
#define CPG 32
#define NTOK 4096
#define EPSV 1e-5f
// scale = hd^-0.5 = 0.125, folded with log2(e) so P = exp2(q'.k)
#define QSCALE 0.1803368801111204f
#define NSPLIT 4

typedef __attribute__((ext_vector_type(8))) short short8;
typedef __attribute__((ext_vector_type(4))) short s4bf;
typedef __attribute__((ext_vector_type(4))) float float4v;

__device__ __forceinline__ unsigned short f2bf(float f) {
    union { float f; unsigned u; } v; v.f = f;
    unsigned r = v.u + 0x7FFF + ((v.u >> 16) & 1);
    return (unsigned short)(r >> 16);
}
__device__ __forceinline__ unsigned short f2bf_fast(float f) {
    union { float f; unsigned u; } v; v.f = f;
    return (unsigned short)((v.u + 0x8000u) >> 16);
}
__device__ __forceinline__ float bf2f(unsigned short u) {
    union { unsigned u; float f; } v; v.u = ((unsigned)u) << 16;
    return v.f;
}
// pack two f32 -> one VGPR holding two bf16 (RNE, same results as f2bf)
__device__ __forceinline__ unsigned pk2bf(float a, float b) {
#if __has_builtin(__builtin_amdgcn_cvt_pk_bf16_f32)
    typedef __attribute__((ext_vector_type(2))) __bf16 bf2v;
    bf2v p = __builtin_amdgcn_cvt_pk_bf16_f32(a, b);
    union { bf2v v; unsigned u; } c; c.v = p;
    return c.u;
#else
    return (unsigned)f2bf_fast(a) | ((unsigned)f2bf_fast(b) << 16);
#endif
}

// async global->LDS DMA, 16B per lane; dst must be wave-uniform (HW adds lane*16)
#define GL2LDS(g, l) __builtin_amdgcn_global_load_lds( \
    (const __attribute__((address_space(1))) void*)(g), \
    (__attribute__((address_space(3))) void*)(l), 16, 0, 0)

// ---------------- prep: fused wcvt + gn_partial (independent work) ----------------
__global__ void prep(const float* __restrict__ x,
                     const float* __restrict__ qkv_w, const float* __restrict__ qkv_b,
                     const float* __restrict__ proj_w,
                     float* __restrict__ psum, float* __restrict__ psq,
                     unsigned short* __restrict__ wq, float* __restrict__ bq,
                     unsigned short* __restrict__ wp) {
    int bx = blockIdx.x;
    int t = threadIdx.x;
    if (bx < 256) {
        // -------- gn_partial --------
        int s = bx & 15, g = (bx >> 4) & 7, b = bx >> 7;
        const float* base = x + ((size_t)(b * CH + g * CPG)) * NTOK + (size_t)s * 8192;
        float sum = 0.f, sq = 0.f;
        const float4v* p4 = (const float4v*)base;
        for (int i = 0; i < 8; ++i) {
            float4v v = p4[t + i * 256];
            for (int j = 0; j < 4; ++j) { sum += v[j]; sq += v[j] * v[j]; }
        }
        for (int off = 32; off; off >>= 1) {
            sum += __shfl_down(sum, off, 64);
            sq  += __shfl_down(sq,  off, 64);
        }
        __shared__ float ls[8];
        int wave = t >> 6, lane = t & 63;
        if (lane == 0) { ls[wave * 2] = sum; ls[wave * 2 + 1] = sq; }
        __syncthreads();
        if (t == 0) {
            float S = 0.f, Q = 0.f;
            for (int w = 0; w < 4; ++w) { S += ls[w * 2]; Q += ls[w * 2 + 1]; }
            int idx = (b * NGROUP + g) * 16 + s;
            psum[idx] = S; psq[idx] = Q;
        }
    } else {
        // -------- wcvt --------
        int idx = (bx - 256) * 256 + t;
        int stride = 256 * 256;
        for (int i = idx; i < 3 * CH * CH; i += stride) {
            float f = qkv_w[i];
            if (i < CH * CH) f *= QSCALE;
            wq[i] = f2bf(f);
        }
        for (int i = idx; i < CH * CH; i += stride) wp[i] = f2bf(proj_w[i]);
        for (int i = idx; i < 3 * CH; i += stride) {
            float f = qkv_b[i];
            if (i < CH) f *= QSCALE;
            bq[i] = f;
        }
    }
}

// ---------------- QKV GEMM with fused GroupNorm + transposed q/k/v stores ----------------
// (R9-verified: fused GN staging from x; q/k AND v transposed via LDS -> coalesced
// 128B short8 row stores.)
__global__ __launch_bounds__(256) void qkv_gemm(const float* __restrict__ x,
        const float* __restrict__ nw, const float* __restrict__ nb_,
        const float* __restrict__ psum, const float* __restrict__ psq,
        const unsigned short* __restrict__ wq, const float* __restrict__ bq,
        unsigned short* __restrict__ qT, unsigned short* __restrict__ kT,
        unsigned short* __restrict__ vv) {
    // XCD remap: all 12 ob-blocks of one (nb,b) tile on the same XCD (shares x tile in L2)
    int f = blockIdx.x + 64 * blockIdx.y + 768 * blockIdx.z;   // 0..1535
    int xcd = f & 7, j = f >> 3;        // j: 0..191
    int ob = j % 12;                    // 0..11
    int p  = xcd + 8 * (j / 12);        // 0..127
    int nb = p & 63;                    // 0..63
    int b  = p >> 6;                    // 0..1
    int t = threadIdx.x;
    int wave = t >> 6, lane = t & 63;
    int l15 = lane & 15, quad = lane >> 4;
    int o0 = ob * 64 + wave * 16;

    __shared__ __align__(16) unsigned short bt[64 * 264];   // B tile; reused as transpose buf
    __shared__ float wch[256], bch[256];                     // per-channel affine

    // ---- per-channel scale/shift from partial stats (one channel per thread)
    {
        int c = t;
        int gg = c >> 5;
        float S = 0.f, Q = 0.f;
        for (int s = 0; s < 16; ++s) {
            S += psum[(b * NGROUP + gg) * 16 + s];
            Q += psq[(b * NGROUP + gg) * 16 + s];
        }
        const float M = (float)(CPG * NTOK);
        float mean = S / M;
        float inv  = rsqrtf(Q / M - mean * mean + EPSV);
        float w = nw[c] * inv;
        wch[c] = w;
        bch[c] = nb_[c] - mean * w;
    }

    short8 aW[8];
    {
        const unsigned short* wr = wq + (size_t)(o0 + l15) * CH + quad * 8;
        for (int kc = 0; kc < 8; ++kc) aW[kc] = *(const short8*)(wr + kc * 32);
    }
    __syncthreads();   // wch/bch ready

    // ---- stage normalized B tile [64 n][256 c] bf16 directly from x
    {
        int n = t & 63, jj = t >> 6;     // jj: 0..3
        const float* xb = x + (size_t)b * CH * NTOK + (size_t)nb * 64 + n;
        for (int i = 0; i < 16; ++i) {
            int c0 = i * 16 + jj * 4;
            float h0 = xb[(size_t)(c0 + 0) * NTOK] * wch[c0 + 0] + bch[c0 + 0];
            float h1 = xb[(size_t)(c0 + 1) * NTOK] * wch[c0 + 1] + bch[c0 + 1];
            float h2 = xb[(size_t)(c0 + 2) * NTOK] * wch[c0 + 2] + bch[c0 + 2];
            float h3 = xb[(size_t)(c0 + 3) * NTOK] * wch[c0 + 3] + bch[c0 + 3];
            union { s4bf v; unsigned u[2]; } pk;
            pk.u[0] = pk2bf(h0, h1);
            pk.u[1] = pk2bf(h2, h3);
            *(s4bf*)(bt + n * 264 + c0) = pk.v;
        }
    }
    __syncthreads();

    float4v acc[4];
    for (int nt = 0; nt < 4; ++nt) for (int r = 0; r < 4; ++r) acc[nt][r] = 0.f;
    for (int kc = 0; kc < 8; ++kc) {
        for (int nt = 0; nt < 4; ++nt) {
            short8 pb = *(const short8*)(bt + (nt * 16 + l15) * 264 + kc * 32 + quad * 8);
            acc[nt] = __builtin_amdgcn_mfma_f32_16x16x32_bf16(aW[kc], pb, acc[nt], 0, 0, 0);
        }
    }
    // seg is block-uniform: o in [ob*64, ob*64+64)
    int seg = ob >> 2;         // 0=q (pre-scaled), 1=k, 2=v
    if (seg < 2) {
        // one head's [64 n][64 hd] tile -> transpose via LDS, coalesced row stores
        int hh = ob & 3;
        unsigned short* dst = (seg == 0) ? qT : kT;
        unsigned short* ot = bt;             // reuse (stride 72 shorts)
        __syncthreads();                     // everyone done reading bt
        for (int nt = 0; nt < 4; ++nt) {
            int ob_ = o0 + quad * 4;
            s4bf pk;
            for (int r = 0; r < 4; ++r)
                pk[r] = (short)f2bf(acc[nt][r] + bq[ob_ + r]);
            int ci = wave * 16 + quad * 4;   // channel within head
            *(s4bf*)(ot + (nt * 16 + l15) * 72 + ci) = pk;
        }
        __syncthreads();
        for (int ii = 0; ii < 2; ++ii) {
            int id2 = ii * 256 + t;
            int n = id2 >> 3, c16 = id2 & 7;
            short8 row = *(const short8*)(ot + n * 72 + c16 * 8);
            *(short8*)(dst + (((size_t)b * NH + hh) * NTOK + (size_t)nb * 64 + n) * HD + c16 * 8) = row;
        }
    } else {
        // V: one head's [64 ci][64 n] tile in vv[b,h,d,n] -> transpose via LDS,
        // coalesced 128B row stores
        int hh = ob & 3;
        unsigned short* ot = bt;             // [ci=64][n], stride 72 shorts
        __syncthreads();                     // everyone done reading bt
        for (int nt = 0; nt < 4; ++nt) {
            int cib = wave * 16 + quad * 4;  // channel within head (row)
            int ob_ = o0 + quad * 4;
            for (int r = 0; r < 4; ++r)
                ot[(cib + r) * 72 + nt * 16 + l15] = f2bf(acc[nt][r] + bq[ob_ + r]);
        }
        __syncthreads();
        for (int ii = 0; ii < 2; ++ii) {
            int id2 = ii * 256 + t;
            int ci = id2 >> 3, c16 = id2 & 7;
            short8 row = *(const short8*)(ot + ci * 72 + c16 * 8);
            *(short8*)(vv + (((size_t)b * NH + hh) * HD + ci) * NTOK + (size_t)nb * 64 + c16 * 8) = row;
        }
    }
}

// ---------------- Flash attention: S^T trick (register P->PV), 64-key tiles, split x4 ----
// Round-13: (a) STAGE reverted to the R5 table form (R9's incremental pointers kept
// 4 pointers live across the loop and serialized DMA issue: 56.2 -> 58.7 regress).
// (b) PV loop reorder ct-outer/nt-inner -> nt-outer/ct-inner: all 8 (mt,ct)
// accumulators are independent within each nt step (dependency distance 8 MFMAs,
// was 1 with 2-way ILP) -- hides MFMA latency. Per-accumulator accumulation order
// over nt is unchanged (0,1,2,3) -> bitwise-identical numerics.
__global__ __launch_bounds__(256, 4) void attn_kernel(const unsigned short* __restrict__ qT,
        const unsigned short* __restrict__ kT, const unsigned short* __restrict__ vv,
        unsigned short* __restrict__ opb, float* __restrict__ lpb) {
    // ---- bijective XCD swizzle: f = flat id; hw assigns XCD = f & 7 (round-robin).
    // group g = h + 4*zb (32 groups share one K/V chunk); give each XCD 4 whole groups.
    int f = blockIdx.x + 32 * blockIdx.y + 128 * blockIdx.z;   // 0..1023
    int xcd = f & 7, j = f >> 3;                                // j: 0..127
    int nb = j >> 2;                                            // 0..31
    int g  = xcd + 8 * (j & 3);                                 // 0..31
    int h  = g & 3;
    int zb = g >> 2;
    int sp = zb & 3, b = zb >> 2;
    int t = threadIdx.x, wave = t >> 6, lane = t & 63;
    int l15 = lane & 15, quad = lane >> 4;
    int n0 = nb * 128 + wave * 32;     // wave owns 2 m-tiles of 16 rows
    int kv0 = sp * (NTOK / NSPLIT);

    unsigned short* opart = opb + (size_t)sp * ((size_t)BATCH * NTOK * CH);
    float* lpart = lpb + (size_t)sp * (BATCH * NH * NTOK);

    const unsigned short* qbh = qT + ((size_t)(b * NH + h)) * NTOK * HD;
    const unsigned short* kbh = kT + ((size_t)(b * NH + h)) * NTOK * HD;
    const unsigned short* vbh = vv + ((size_t)(b * NH + h)) * HD * NTOK;

    // double-buffered tiles (32 KB total)
    __shared__ __align__(16) unsigned short kbuf[2][64 * 64];
    __shared__ __align__(16) unsigned short vbuf[2][64 * 64];

    short8 aQ[2][2];   // B-fragment of QK: B[q-row=l15][hd k=quad*8+j]
    for (int mt = 0; mt < 2; ++mt) {
        aQ[mt][0] = *(const short8*)(qbh + (size_t)(n0 + mt * 16 + l15) * HD + quad * 8);
        aQ[mt][1] = *(const short8*)(qbh + (size_t)(n0 + mt * 16 + l15) * HD + 32 + quad * 8);
    }

    float l_p[2] = {0.f, 0.f};         // per-lane partial denom (q-row = l15)
    float4v o_acc[2][4];
    for (int mt = 0; mt < 2; ++mt)
        for (int ct = 0; ct < 4; ++ct)
            for (int r = 0; r < 4; ++r) o_acc[mt][ct][r] = 0.f;
    const float4v ZERO = {0.f, 0.f, 0.f, 0.f};   // hoisted QK C-input

    // ---- issue one 64-key tile's K+V DMA: 4 x global_load_lds per wave (16B/lane)
    // K tile [key r][d]: 128B rows, 8 chunks; src chunk = c ^ (r&7)
    // V tile [d r][key]: 128B rows, 8 chunks; src chunk = c ^ (r&7)
    #define STAGE_TILE(kb_, vb_, ms_)                                                  \
        do {                                                                           \
            _Pragma("unroll")                                                          \
            for (int i = 0; i < 2; ++i) {                                              \
                int slot = (wave * 2 + i) * 64 + lane;                                 \
                int r = slot >> 3, c = slot & 7;                                       \
                GL2LDS(kbh + (size_t)((ms_) + r) * HD + ((c ^ (r & 7)) << 3),          \
                       (kb_) + (wave * 2 + i) * 512);                                  \
            }                                                                          \
            _Pragma("unroll")                                                          \
            for (int i = 0; i < 2; ++i) {                                              \
                int slot = (wave * 2 + i) * 64 + lane;                                 \
                int r = slot >> 3, c = slot & 7;                                       \
                GL2LDS(vbh + (size_t)r * NTOK + (ms_) + ((c ^ (r & 7)) << 3),          \
                       (vb_) + (wave * 2 + i) * 512);                                  \
            }                                                                          \
        } while (0)

    STAGE_TILE(kbuf[0], vbuf[0], kv0);
    int cur = 0;

    for (int ms = kv0; ms < kv0 + NTOK / NSPLIT; ms += 64) {
        // own DMA landed; barrier => all waves' DMA landed AND prev compute done
        asm volatile("s_waitcnt vmcnt(0)" ::: "memory");
        __syncthreads();
        if (ms + 64 < kv0 + NTOK / NSPLIT)
            STAGE_TILE(kbuf[cur ^ 1], vbuf[cur ^ 1], ms + 64);   // in flight under compute
        const unsigned short* kb = kbuf[cur];
        const unsigned short* vb = vbuf[cur];

        float4v s[2][4];
        __builtin_amdgcn_s_setprio(1);
#pragma unroll
        for (int nt = 0; nt < 4; ++nt) {
            int krow = nt * 16 + l15;
            int r7 = krow & 7;
            short8 ak0 = *(const short8*)(kb + krow * 64 + ((quad ^ r7) << 3));
            short8 ak1 = *(const short8*)(kb + krow * 64 + (((quad + 4) ^ r7) << 3));
#pragma unroll
            for (int mt = 0; mt < 2; ++mt) {
                float4v z = __builtin_amdgcn_mfma_f32_16x16x32_bf16(ak0, aQ[mt][0], ZERO, 0, 0, 0);
                z = __builtin_amdgcn_mfma_f32_16x16x32_bf16(ak1, aQ[mt][1], z, 0, 0, 0);
                s[mt][nt] = z;
            }
        }
        __builtin_amdgcn_s_setprio(0);
        s4bf aP[2][4];
#pragma unroll
        for (int mt = 0; mt < 2; ++mt) {
#pragma unroll
            for (int nt = 0; nt < 4; ++nt) {
                float e0 = __builtin_amdgcn_exp2f(s[mt][nt][0]);
                float e1 = __builtin_amdgcn_exp2f(s[mt][nt][1]);
                float e2 = __builtin_amdgcn_exp2f(s[mt][nt][2]);
                float e3 = __builtin_amdgcn_exp2f(s[mt][nt][3]);
                l_p[mt] += (e0 + e1) + (e2 + e3);
                union { s4bf v; unsigned u[2]; } c;
                c.u[0] = pk2bf(e0, e1);
                c.u[1] = pk2bf(e2, e3);
                aP[mt][nt] = c.v;
            }
        }
        __builtin_amdgcn_s_setprio(1);
        // PV: nt-outer/ct-inner -> 8 independent accumulator chains per nt step.
        // Accumulation order over nt per o_acc[mt][ct] unchanged (bitwise identical).
#pragma unroll
        for (int nt = 0; nt < 4; ++nt) {
#pragma unroll
            for (int ct = 0; ct < 4; ++ct) {
                int vr = ct * 16 + l15;
                int c8 = nt * 2 + (quad >> 1);
                s4bf bv = *(const s4bf*)(vb + vr * 64 +
                                         ((c8 ^ (vr & 7)) << 3) + ((quad & 1) << 2));
#pragma unroll
                for (int mt = 0; mt < 2; ++mt)
                    o_acc[mt][ct] = __builtin_amdgcn_mfma_f32_16x16x16bf16_1k(aP[mt][nt], bv, o_acc[mt][ct], 0, 0, 0);
            }
        }
        __builtin_amdgcn_s_setprio(0);
        cur ^= 1;
    }
    // reduce denom over the 4 quads (key blocks); q-row = l15
    for (int mt = 0; mt < 2; ++mt) {
        l_p[mt] += __shfl_xor(l_p[mt], 16, 64);
        l_p[mt] += __shfl_xor(l_p[mt], 32, 64);
    }
    // store unnormalized partial O (bf16): C-layout col=l15=d, row=quad*4+r=q-row
    for (int mt = 0; mt < 2; ++mt) {
        for (int ct = 0; ct < 4; ++ct) {
            for (int r = 0; r < 4; ++r) {
                int n = n0 + mt * 16 + quad * 4 + r;
                int cg = h * HD + ct * 16 + l15;
                opart[((size_t)b * NTOK + n) * CH + cg] = f2bf(o_acc[mt][ct][r]);
            }
        }
        if (lane < 16)
            lpart[((size_t)(b * NH + h)) * NTOK + n0 + mt * 16 + lane] = l_p[mt];
    }
}

// ---------------- Proj GEMM with fused split-combine + bias + residual ----------------
__global__ __launch_bounds__(256) void proj_gemm(const unsigned short* __restrict__ opb,
        const float* __restrict__ lpb, const unsigned short* __restrict__ wp,
        const float* __restrict__ proj_b, const float* __restrict__ x,
        float* __restrict__ out) {
    int f = blockIdx.x + 64 * blockIdx.y + 256 * blockIdx.z;   // 0..511
    int xcd = f & 7, j = f >> 3;    // j: 0..63
    int cb = j & 3;                 // 0..3
    int p  = xcd + 8 * (j >> 2);    // 0..127
    int nb = p & 63;                // 0..63
    int b  = p >> 6;                // 0..1
    int t = threadIdx.x, wave = t >> 6, lane = t & 63;
    int l15 = lane & 15, quad = lane >> 4;
    int c0 = cb * 64 + wave * 16;
    const size_t OP = (size_t)BATCH * NTOK * CH;
    const size_t LP = (size_t)BATCH * NH * NTOK;

    __shared__ __align__(16) unsigned short bt[64 * 264];
    __shared__ float rl[64 * 4];

    short8 aW[8];
    {
        const unsigned short* wr = wp + (size_t)(c0 + l15) * CH + quad * 8;
        for (int kc = 0; kc < 8; ++kc) aW[kc] = *(const short8*)(wr + kc * 32);
    }
    // per-row, per-head reciprocal denominators (normalization must precede channel-sum)
    {
        int r = t >> 2, h = t & 3;
        size_t lidx = ((size_t)(b * NH + h)) * NTOK + nb * 64 + r;
        float ls = (lpb[lidx] + lpb[LP + lidx]) + (lpb[2 * LP + lidx] + lpb[3 * LP + lidx]);
        rl[r * 4 + h] = 1.0f / ls;
    }
    __syncthreads();
    // stage normalized O tile from the 4 split partials
    for (int p2 = 0; p2 < 8; ++p2) {
        int slot = p2 * 256 + t;
        int r = slot >> 5, c = slot & 31;
        size_t base = ((size_t)b * NTOK + nb * 64 + r) * CH + c * 8;
        short8 o0 = *(const short8*)(opb + base);
        short8 o1 = *(const short8*)(opb + OP + base);
        short8 o2 = *(const short8*)(opb + 2 * OP + base);
        short8 o3 = *(const short8*)(opb + 3 * OP + base);
        float rinv = rl[r * 4 + (c >> 3)];
        short8 m;
        for (int jj = 0; jj < 8; ++jj) {
            float ff = (bf2f((unsigned short)o0[jj]) + bf2f((unsigned short)o1[jj]))
                     + (bf2f((unsigned short)o2[jj]) + bf2f((unsigned short)o3[jj]));
            m[jj] = (short)f2bf(ff * rinv);
        }
        *(short8*)(bt + r * 264 + c * 8) = m;
    }
    __syncthreads();

    float4v acc[4];
    for (int nt = 0; nt < 4; ++nt) for (int r = 0; r < 4; ++r) acc[nt][r] = 0.f;
    for (int kc = 0; kc < 8; ++kc) {
        for (int nt = 0; nt < 4; ++nt) {
            short8 pb = *(const short8*)(bt + (nt * 16 + l15) * 264 + kc * 32 + quad * 8);
            acc[nt] = __builtin_amdgcn_mfma_f32_16x16x32_bf16(aW[kc], pb, acc[nt], 0, 0, 0);
        }
    }
    for (int nt = 0; nt < 4; ++nt) {
        int n = nb * 64 + nt * 16 + l15;
        for (int r = 0; r < 4; ++r) {
            int cc = c0 + quad * 4 + r;
            size_t idx = ((size_t)(b * CH + cc)) * NTOK + n;
            out[idx] = acc[nt][r] + proj_b[cc] + x[idx];
        }
    }
}

extern "C" void kernel_launch(void* const* d_in, const int* in_sizes, int n_in,
                              void* d_out, int out_size, void* d_ws, size_t ws_size,
                              hipStream_t stream) {
    const float* x      = (const float*)d_in[0];
    const float* norm_w = (const float*)d_in[1];
    const float* norm_b = (const float*)d_in[2];
    const float* qkv_w  = (const float*)d_in[3];
    const float* qkv_b  = (const float*)d_in[4];
    const float* proj_w = (const float*)d_in[5];
    const float* proj_b = (const float*)d_in[6];
    float* out = (float*)d_out;

    char* ws = (char*)d_ws;
    float* psum  = (float*)ws;                       // 256 f
    float* psq   = (float*)(ws + 1024);              // 256 f
    float* bqs   = (float*)(ws + 4096);              // 768 f
    unsigned short* wqb = (unsigned short*)(ws + 8192);        // 3*256*256 bf16
    unsigned short* wpb = (unsigned short*)(ws + 401408);      // 256*256 bf16
    float* lpb = (float*)(ws + 532480);              // 4 * 2*4*4096 f
    const size_t MB4 = 4194304;
    unsigned short* opb = (unsigned short*)(ws + 2097152);     // 4 x 4 MB partials
    unsigned short* qT = (unsigned short*)(ws + 2097152 + 4 * MB4);
    unsigned short* kT = (unsigned short*)(ws + 2097152 + 5 * MB4);
    unsigned short* vv = (unsigned short*)(ws + 2097152 + 6 * MB4);

    prep<<<dim3(512), dim3(256), 0, stream>>>(x, qkv_w, qkv_b, proj_w, psum, psq, wqb, bqs, wpb);
    qkv_gemm<<<dim3(64, 12, BATCH), dim3(256), 0, stream>>>(x, norm_w, norm_b, psum, psq,
                                                            wqb, bqs, qT, kT, vv);
    attn_kernel<<<dim3(32, NH, BATCH * NSPLIT), dim3(256), 0, stream>>>(qT, kT, vv, opb, lpb);
    proj_gemm<<<dim3(64, 4, BATCH), dim3(256), 0, stream>>>(opb, lpb, wpb, proj_b, x, out);
}